// Round 9
// baseline (2808.746 us; speedup 1.0000x reference)
//
#include <hip/hip_runtime.h>
#include <hip/hip_bf16.h>

#define B_GRAPHS 64
#define NPER     2048
#define T_NODES  (B_GRAPHS*NPER)
#define D_DIM    256
#define U_DIM    128
#define TU       384   // 3*U
#define XPW      768   // 2*TU (fwd|bwd)

typedef unsigned short ushortT;
typedef unsigned int   uint32;

typedef __attribute__((ext_vector_type(4))) float  f32x4;
typedef __attribute__((ext_vector_type(8))) __bf16 bf16x8;
typedef _Float16 f16;
typedef __attribute__((ext_vector_type(8))) _Float16 f16x8;

#define GAS __attribute__((address_space(1)))
#define LOG2E_F 1.4426950408889634f

static __device__ __forceinline__ ushortT f2bf(float f) {
  union { float f; uint32 u; } a; a.f = f;
  uint32 u = a.u;
  return (ushortT)((u + 0x7fffu + ((u >> 16) & 1u)) >> 16);   // RTNE
}
static __device__ __forceinline__ float bf2f(ushortT h) {
  union { uint32 u; float f; } a; a.u = ((uint32)h) << 16; return a.f;
}
static __device__ __forceinline__ float rcpf(float x) {
#if __has_builtin(__builtin_amdgcn_rcpf)
  return __builtin_amdgcn_rcpf(x);
#else
  return 1.0f / x;
#endif
}
static __device__ __forceinline__ float exp2f_hw(float x) {
#if __has_builtin(__builtin_amdgcn_exp2f)
  return __builtin_amdgcn_exp2f(x);
#else
  return __expf(0.69314718055994531f * x);
#endif
}
static __device__ __forceinline__ ushortT gload_u16(const ushortT* p) {
  return *(const GAS ushortT*)p;
}
static __device__ __forceinline__ void gstore_u16(ushortT* p, ushortT v) {
  *(GAS ushortT*)p = v;
}

// ---------------- prep: Wt[2][768][256] bf16 (transposed concat of K_fwd|K_bwd), b0[2][768] f32
// NOTE: z,r columns prescaled by log2e; h columns by 2*log2e (lets rec use exp2 directly).
__global__ __launch_bounds__(256) void prep_kernel(
    const float* __restrict__ Kf, const float* __restrict__ Kb,
    const float* __restrict__ bfw, const float* __restrict__ bbw,
    ushortT* __restrict__ Wt, float* __restrict__ b0)
{
  int idx = blockIdx.x * 256 + threadIdx.x;
  if (idx < 2 * XPW * D_DIM) {
    int l = idx / (XPW * D_DIM);
    int rem = idx % (XPW * D_DIM);
    int c = rem / D_DIM, k = rem % D_DIM;
    float v = (c < TU) ? Kf[(size_t)l * D_DIM * TU + (size_t)k * TU + c]
                       : Kb[(size_t)l * D_DIM * TU + (size_t)k * TU + (c - TU)];
    float sc = ((c % TU) < 256) ? LOG2E_F : 2.0f * LOG2E_F;
    Wt[idx] = f2bf(v * sc);
  } else {
    int i2 = idx - 2 * XPW * D_DIM;
    if (i2 < 2 * XPW) {
      int l = i2 / XPW, c = i2 % XPW;
      float v = (c < TU) ? bfw[l * 2 * TU + c] : bbw[l * 2 * TU + (c - TU)];
      float sc = ((c % TU) < 256) ? LOG2E_F : 2.0f * LOG2E_F;
      b0[i2] = v * sc;
    }
  }
}

// ---------------- nodeof[g][slot] = node index ; L[g] = leaf count (positions are a perm of 1..L)
__global__ __launch_bounds__(256) void nodeofL_kernel(
    const int* __restrict__ pos, int* __restrict__ nodeof, int* __restrict__ L)
{
  int g = blockIdx.x, tid = threadIdx.x;
  __shared__ int red[256];
  int cnt = 0;
  for (int i = 0; i < NPER / 256; ++i) {
    int t = g * NPER + i * 256 + tid;
    int p = pos[t];
    if (p) { nodeof[g * NPER + p - 1] = t; cnt++; }
  }
  red[tid] = cnt; __syncthreads();
  for (int s = 128; s > 0; s >>= 1) {
    if (tid < s) red[tid] += red[tid + s];
    __syncthreads();
  }
  if (tid == 0) L[g] = red[0];
}

#if __has_builtin(__builtin_amdgcn_global_load_lds)
#define GLD_LDS(gsrc, ldst) \
  __builtin_amdgcn_global_load_lds((const GAS void*)(gsrc), \
                                   (__attribute__((address_space(3))) void*)(ldst), 16, 0, 0)
#define HAVE_GLD_LDS 1
#else
#define HAVE_GLD_LDS 0
#endif

// ---------------- xp[row][768] = A[row][0..255] @ Wt^T + b0   (bf16 MFMA, 128x128 tiles, BK=32)
// mode 0: A row r gathered from states (f32 -> bf16) via nodeof ; mode 1: A = dense bf16 (y)
__global__ __launch_bounds__(256) void gemm_kernel(
    const float* __restrict__ statesA, const ushortT* __restrict__ Adense,
    const ushortT* __restrict__ Wt, const float* __restrict__ b0,
    const int* __restrict__ nodeof, const int* __restrict__ L,
    ushortT* __restrict__ xp, int layer, int mode)
{
  int mblk = blockIdx.x, nblk = blockIdx.y;
  int g = mblk >> 4;
  int sBase = (mblk & 15) << 7;
  int Lg = L[g];
  if (sBase >= Lg) return;   // whole row-block is padding

  __shared__ __align__(16) ushortT As[128 * 32];
  __shared__ __align__(16) ushortT Bs[128 * 32];

  int tid = threadIdx.x;
  int lane = tid & 63, wid = tid >> 6;
  int wr = wid >> 1, wc = wid & 1;
  f32x4 acc[4][4];
  for (int i = 0; i < 4; i++) for (int n = 0; n < 4; n++) acc[i][n] = (f32x4){0.f,0.f,0.f,0.f};

  for (int kb = 0; kb < 8; ++kb) {
    __syncthreads();
    // stage B: Wt tile [128 cols][32 k] (Wt is pre-transposed: row=col, 512B row stride)
    for (int c = 0; c < 2; ++c) {
      int flat = c * 4096 + tid * 16;
      int col = flat >> 6;
      size_t srcB = ((size_t)(layer * XPW + nblk * 128 + col)) * 512 + kb * 64 + (flat & 63);
#if HAVE_GLD_LDS
      GLD_LDS((const char*)Wt + srcB, (char*)Bs + c * 4096 + wid * 1024);
#else
      *(uint4*)((char*)Bs + flat) = *(const uint4*)((const char*)Wt + srcB);
#endif
    }
    // stage A
    if (mode) {
      for (int c = 0; c < 2; ++c) {
        int flat = c * 4096 + tid * 16;
        int row = flat >> 6;
        size_t srcA = ((size_t)(mblk * 128 + row)) * 512 + kb * 64 + (flat & 63);
#if HAVE_GLD_LDS
        GLD_LDS((const char*)Adense + srcA, (char*)As + c * 4096 + wid * 1024);
#else
        *(uint4*)((char*)As + flat) = *(const uint4*)((const char*)Adense + srcA);
#endif
      }
    } else {
      for (int c = 0; c < 2; ++c) {
        int flat = c * 4096 + tid * 16;
        int row = flat >> 6;
        int s = sBase + row;
        if (s < Lg) {
          int nt = nodeof[g * NPER + s];
          const float* sp = statesA + (size_t)nt * D_DIM + kb * 32 + ((flat & 63) >> 1);
          float4 u0 = *(const float4*)sp;
          float4 u1 = *(const float4*)(sp + 4);
          union { ushortT us[8]; uint4 v; } pk;
          pk.us[0] = f2bf(u0.x); pk.us[1] = f2bf(u0.y); pk.us[2] = f2bf(u0.z); pk.us[3] = f2bf(u0.w);
          pk.us[4] = f2bf(u1.x); pk.us[5] = f2bf(u1.y); pk.us[6] = f2bf(u1.z); pk.us[7] = f2bf(u1.w);
          *(uint4*)((char*)As + flat) = pk.v;
        }
      }
    }
    __syncthreads();

    bf16x8 af[4], bfr[4];
    for (int i = 0; i < 4; i++) {
      int off = (wr * 64 + i * 16 + (lane & 15)) * 32 + (lane >> 4) * 8;
      af[i] = *(const bf16x8*)&As[off];
    }
    for (int n = 0; n < 4; n++) {
      int off = (wc * 64 + n * 16 + (lane & 15)) * 32 + (lane >> 4) * 8;
      bfr[n] = *(const bf16x8*)&Bs[off];
    }
    for (int i = 0; i < 4; i++)
      for (int n = 0; n < 4; n++)
        acc[i][n] = __builtin_amdgcn_mfma_f32_16x16x32_bf16(af[i], bfr[n], acc[i][n], 0, 0, 0);
  }

  // epilogue: + bias, store bf16.  C/D layout: col = lane&15, row = (lane>>4)*4 + v
  for (int n = 0; n < 4; n++) {
    int gcol = nblk * 128 + wc * 64 + n * 16 + (lane & 15);
    float bb = b0[layer * XPW + gcol];
    for (int i = 0; i < 4; i++) {
      int rowBase = mblk * 128 + wr * 64 + i * 16 + (lane >> 4) * 4;
      for (int v = 0; v < 4; v++)
        xp[(size_t)(rowBase + v) * XPW + gcol] = f2bf(acc[i][n][v] + bb);
    }
  }
}

// ---------------- recurrence (MFMA-batched, 4 waves): 1 WG (256 thr) per (16 graphs, dir).
// Wave w owns unit-tiles {w, w+4} => cols j0 = w*16+jc and j1 = j0+64 for all 3 gates.
// A-frags (H rows=chains) are read ONCE per wave per step and shared by both tiles.
// 24 MFMA/wave/step, 8 gate-triples/lane. 1 wave/SIMD (high VGPR) => minimal per-step
// sync/LDS serialization (r5-r8 scaling law: step ~ 200cyc x waves + fixed).
// Depth-2 xp prefetch (static XA/XB buffers, unroll-2 loop). One raw s_barrier per step,
// lgkmcnt-only drain (xp loads / y stores vmcnt-only, stay in flight).
__global__ __launch_bounds__(256) void rec_kernel(
    const ushortT* __restrict__ xp,
    const float* __restrict__ Rf, const float* __restrict__ Rb,
    const float* __restrict__ bfw, const float* __restrict__ bbw,
    const int* __restrict__ L, ushortT* __restrict__ y, int layer)
{
  int dir = blockIdx.y;
  int g0 = blockIdx.x * 16;
  int tid = threadIdx.x;
  int wave = tid >> 6, lane = tid & 63;
  int jc = lane & 15;           // A-row (chain) for A-frags AND col-within-tile for D
  int qa = lane >> 4;           // 0..3
  int j0 = wave * 16 + jc;      // unit index, tile ut0 = wave
  int j1 = j0 + 64;             // unit index, tile ut1 = wave+4

  __shared__ __align__(16) ushortT Hb[2][16 * 128];   // f16 bits, swizzled

  int Lmax = 0;
  #pragma unroll 1
  for (int i = 0; i < 16; ++i) { int t = L[g0 + i]; Lmax = t > Lmax ? t : Lmax; }
  if (Lmax == 0) return;
  int Lg4[4];
  #pragma unroll
  for (int v = 0; v < 4; ++v) Lg4[v] = L[g0 + qa * 4 + v];

  const float* Rsrc = (dir ? Rb : Rf) + (size_t)layer * U_DIM * TU;
  const float* b1p  = (dir ? bbw : bfw) + layer * 2 * TU + TU;

  // preload B-frags (R columns, f16, prescaled) + biases, for both tiles
  f16x8 bw[2][3][4];
  float b1s[2][3];
  #pragma unroll
  for (int t = 0; t < 2; ++t) {
    int jj = t ? j1 : j0;
    #pragma unroll
    for (int gate = 0; gate < 3; ++gate) {
      float sc = (gate < 2) ? LOG2E_F : 2.0f * LOG2E_F;
      int col = gate * 128 + jj;
      b1s[t][gate] = b1p[col] * sc;
      #pragma unroll
      for (int q = 0; q < 4; ++q) {
        union { f16 h[8]; f16x8 v; } pk;
        #pragma unroll
        for (int e = 0; e < 8; ++e) {
          int k = q * 32 + qa * 8 + e;
          pk.h[e] = (f16)(Rsrc[(size_t)k * TU + col] * sc);
        }
        bw[t][gate][q] = pk.v;
      }
    }
  }

  // zero both H buffers
  for (int i = tid; i < 16 * 128; i += 256) { Hb[0][i] = 0; Hb[1][i] = 0; }
  float hold0[4] = {0.f,0.f,0.f,0.f}, hold1[4] = {0.f,0.f,0.f,0.f};
  __syncthreads();

  // rolling pointers (per chain v), based at j0
  const ushortT* xptr[4];
  ushortT* yptr[4];
  #pragma unroll
  for (int v = 0; v < 4; ++v) {
    int c = qa * 4 + v;
    int Lg = Lg4[v];
    int pos0 = dir ? (Lg > 0 ? Lg - 1 : 0) : 0;
    xptr[v] = xp + ((size_t)(g0 + c) * NPER + pos0) * XPW + dir * TU + j0;
    yptr[v] = y  + ((size_t)(g0 + c) * NPER + pos0) * D_DIM + dir * U_DIM + j0;
  }
  const int xstep = dir ? -XPW : XPW;
  const int ystep = dir ? -D_DIM : D_DIM;

  const int abase = jc * 256 + qa * 16;   // + q*64, then XOR
  const int aswz  = (jc & 7) << 4;
  // H write byte offsets (constant per lane): (c*256 + j*2) ^ ((c&7)<<4)
  int wb0[4], wb1[4];
  #pragma unroll
  for (int v = 0; v < 4; ++v) {
    int c = qa * 4 + v;
    wb0[v] = (c * 256 + j0 * 2) ^ ((c & 7) << 4);
    wb1[v] = (c * 256 + j1 * 2) ^ ((c & 7) << 4);
  }

  // xp load order: idx = v*6 + t*3 + gate ; offsets {0,128,256, 64,192,320}
#define LOADX(X)                                                                 \
  _Pragma("unroll")                                                              \
  for (int v = 0; v < 4; ++v) {                                                  \
    const ushortT* bp = xptr[v];                                                 \
    X[v*6+0] = gload_u16(bp);       X[v*6+1] = gload_u16(bp + 128);              \
    X[v*6+2] = gload_u16(bp + 256); X[v*6+3] = gload_u16(bp + 64);               \
    X[v*6+4] = gload_u16(bp + 192); X[v*6+5] = gload_u16(bp + 320);              \
  }                                                                              \
  _Pragma("unroll")                                                              \
  for (int v = 0; v < 4; ++v) xptr[v] += xstep;

  ushortT XA[24], XB[24];
  LOADX(XA)          // step 0 ; xptr -> pos(1)
  LOADX(XB)          // step 1 ; xptr -> pos(2)

#define GATE(ACCZ, ACCR, ACCH, T, HOLD, XFZ, XFR, XFH, WB, YOFF, S)              \
  {                                                                              \
    float hz = (ACCZ) + b1s[T][0];                                               \
    float hr = (ACCR) + b1s[T][1];                                               \
    float hh = (ACCH) + b1s[T][2];                                               \
    float z = rcpf(1.0f + exp2f_hw(-((XFZ) + hz)));                              \
    float r = rcpf(1.0f + exp2f_hw(-((XFR) + hr)));                              \
    float a = (XFH) + r * hh;                                                    \
    float e = exp2f_hw(__builtin_fabsf(a));                                      \
    float th = 1.0f - 2.0f * rcpf(e + 1.0f);                                     \
    float cand = __builtin_copysignf(th, a);                                     \
    float hnew = cand + z * ((HOLD) - cand);                                     \
    bool live = (S) < Lg4[v];                                                    \
    float hst = live ? hnew : (HOLD);                                            \
    (HOLD) = hst;                                                                \
    if (live) gstore_u16(yptr[v] + (YOFF), f2bf(hst));                           \
    f16 hph = (f16)hst;                                                          \
    *(ushortT*)(Hwr + (WB)) = __builtin_bit_cast(ushortT, hph);                  \
  }

#define STEP(X, P, S)                                                            \
  {                                                                              \
    char* Hrd = (char*)Hb[P];                                                    \
    char* Hwr = (char*)Hb[(P) ^ 1];                                              \
    f16x8 afr[4];                                                                \
    _Pragma("unroll")                                                            \
    for (int q = 0; q < 4; ++q)                                                  \
      afr[q] = *(const f16x8*)(Hrd + ((abase + q * 64) ^ aswz));                 \
    float xf[24];                                                                \
    _Pragma("unroll")                                                            \
    for (int i = 0; i < 24; ++i) xf[i] = bf2f(X[i]);                             \
    LOADX(X)                                                                     \
    f32x4 az0 = {0,0,0,0}, ar0 = {0,0,0,0}, ah0 = {0,0,0,0};                     \
    f32x4 az1 = {0,0,0,0}, ar1 = {0,0,0,0}, ah1 = {0,0,0,0};                     \
    _Pragma("unroll")                                                            \
    for (int q = 0; q < 4; ++q) {                                                \
      az0 = __builtin_amdgcn_mfma_f32_16x16x32_f16(afr[q], bw[0][0][q], az0, 0,0,0); \
      ar0 = __builtin_amdgcn_mfma_f32_16x16x32_f16(afr[q], bw[0][1][q], ar0, 0,0,0); \
      ah0 = __builtin_amdgcn_mfma_f32_16x16x32_f16(afr[q], bw[0][2][q], ah0, 0,0,0); \
      az1 = __builtin_amdgcn_mfma_f32_16x16x32_f16(afr[q], bw[1][0][q], az1, 0,0,0); \
      ar1 = __builtin_amdgcn_mfma_f32_16x16x32_f16(afr[q], bw[1][1][q], ar1, 0,0,0); \
      ah1 = __builtin_amdgcn_mfma_f32_16x16x32_f16(afr[q], bw[1][2][q], ah1, 0,0,0); \
    }                                                                            \
    _Pragma("unroll")                                                            \
    for (int v = 0; v < 4; ++v) {                                                \
      GATE(az0[v], ar0[v], ah0[v], 0, hold0[v], xf[v*6+0], xf[v*6+1], xf[v*6+2], \
           wb0[v], 0,  S)                                                        \
      GATE(az1[v], ar1[v], ah1[v], 1, hold1[v], xf[v*6+3], xf[v*6+4], xf[v*6+5], \
           wb1[v], 64, S)                                                        \
      yptr[v] += ystep;                                                          \
    }                                                                            \
    asm volatile("s_waitcnt lgkmcnt(0)" ::: "memory");                           \
    __builtin_amdgcn_sched_barrier(0);                                           \
    __builtin_amdgcn_s_barrier();                                                \
    __builtin_amdgcn_sched_barrier(0);                                           \
  }

  for (int s = 0; s < Lmax; s += 2) {
    STEP(XA, 0, s)
    if (s + 1 < Lmax) STEP(XB, 1, s + 1)
  }
#undef STEP
#undef GATE
#undef LOADX
}

// ---------------- unpack: leaf -> y (bf16->f32), non-leaf -> states copy
__global__ __launch_bounds__(256) void unpack_kernel(
    const float* __restrict__ states, const int* __restrict__ pos,
    const ushortT* __restrict__ y, float* __restrict__ out)
{
  int node = blockIdx.x * 4 + (threadIdx.x >> 6);
  int lane = threadIdx.x & 63;
  int p = pos[node];
  int g = node >> 11;
  float4 v;
  if (p) {
    const ushortT* yp = y + (size_t)(g * NPER + p - 1) * D_DIM + lane * 4;
    v = make_float4(bf2f(yp[0]), bf2f(yp[1]), bf2f(yp[2]), bf2f(yp[3]));
  } else {
    v = *(const float4*)(states + (size_t)node * D_DIM + lane * 4);
  }
  *(float4*)(out + (size_t)node * D_DIM + lane * 4) = v;
}

extern "C" void kernel_launch(void* const* d_in, const int* in_sizes, int n_in,
                              void* d_out, int out_size, void* d_ws, size_t ws_size,
                              hipStream_t stream) {
  const float* states = (const float*)d_in[0];
  const int*   pos    = (const int*)d_in[1];
  // d_in[2] graph_sizes (uniform 2048), d_in[3] training (0) — unused
  const float* Kf  = (const float*)d_in[4];
  const float* Rf  = (const float*)d_in[5];
  const float* bfw = (const float*)d_in[6];
  const float* Kb  = (const float*)d_in[7];
  const float* Rb  = (const float*)d_in[8];
  const float* bbw = (const float*)d_in[9];

  char* ws = (char*)d_ws;
  // layout: L(256B) | nodeof(512KB) | Wt(768KB) | b0(6KB) | xp(201.3MB) | y(67.1MB)  ~= 270MB
  int*     L      = (int*)(ws + 0);
  int*     nodeof = (int*)(ws + 256);
  ushortT* Wt     = (ushortT*)(ws + 524544);
  float*   b0     = (float*)(ws + 1310976);
  ushortT* xp     = (ushortT*)(ws + 1317120);
  ushortT* y      = (ushortT*)(ws + 202643712);

  prep_kernel<<<1542, 256, 0, stream>>>(Kf, Kb, bfw, bbw, Wt, b0);
  nodeofL_kernel<<<64, 256, 0, stream>>>(pos, nodeof, L);

  dim3 ggrid(1024, 6);
  dim3 rgrid(4, 2);    // 4 WGs of 16 graphs x 2 dirs; 16 chains batched per WG via MFMA

  // layer 0
  gemm_kernel<<<ggrid, 256, 0, stream>>>(states, (const ushortT*)nullptr, Wt, b0, nodeof, L, xp, 0, 0);
  rec_kernel<<<rgrid, 256, 0, stream>>>(xp, Rf, Rb, bfw, bbw, L, y, 0);
  // layer 1
  gemm_kernel<<<ggrid, 256, 0, stream>>>(states, y, Wt, b0, nodeof, L, xp, 1, 1);
  rec_kernel<<<rgrid, 256, 0, stream>>>(xp, Rf, Rb, bfw, bbw, L, y, 1);

  unpack_kernel<<<32768, 256, 0, stream>>>(states, pos, y, (float*)d_out);
}

// Round 10
// 1588.316 us; speedup vs baseline: 1.7684x; 1.7684x over previous
//
#include <hip/hip_runtime.h>
#include <hip/hip_bf16.h>

#define B_GRAPHS 64
#define NPER     2048
#define T_NODES  (B_GRAPHS*NPER)
#define D_DIM    256
#define U_DIM    128
#define TU       384   // 3*U
#define XPW      768   // 2*TU (fwd|bwd)

typedef unsigned short ushortT;
typedef unsigned int   uint32;

typedef __attribute__((ext_vector_type(4))) float  f32x4;
typedef __attribute__((ext_vector_type(8))) __bf16 bf16x8;
typedef _Float16 f16;
typedef __attribute__((ext_vector_type(2))) _Float16 f16x2;

#define GAS __attribute__((address_space(1)))
#define LOG2E_F 1.4426950408889634f

static __device__ __forceinline__ ushortT f2bf(float f) {
  union { float f; uint32 u; } a; a.f = f;
  uint32 u = a.u;
  return (ushortT)((u + 0x7fffu + ((u >> 16) & 1u)) >> 16);   // RTNE
}
static __device__ __forceinline__ float bf2f(ushortT h) {
  union { uint32 u; float f; } a; a.u = ((uint32)h) << 16; return a.f;
}
static __device__ __forceinline__ f16x2 u2h(uint32 u) {
  union { uint32 u; f16x2 h; } x; x.u = u; return x.h;
}
static __device__ __forceinline__ float dot2f(f16x2 a, f16x2 b, float c) {
#if __has_builtin(__builtin_amdgcn_fdot2)
  return __builtin_amdgcn_fdot2(a, b, c, false);
#else
  return c + (float)a.x * (float)b.x + (float)a.y * (float)b.y;
#endif
}
static __device__ __forceinline__ float rcpf(float x) {
#if __has_builtin(__builtin_amdgcn_rcpf)
  return __builtin_amdgcn_rcpf(x);
#else
  return 1.0f / x;
#endif
}
static __device__ __forceinline__ float exp2f_hw(float x) {
#if __has_builtin(__builtin_amdgcn_exp2f)
  return __builtin_amdgcn_exp2f(x);
#else
  return __expf(0.69314718055994531f * x);
#endif
}
static __device__ __forceinline__ ushortT gload_u16(const ushortT* p) {
  return *(const GAS ushortT*)p;
}
static __device__ __forceinline__ void gstore_u16(ushortT* p, ushortT v) {
  *(GAS ushortT*)p = v;
}

// ---------------- prep: Wt[2][768][256] bf16 (transposed concat of K_fwd|K_bwd), b0[2][768] f32
// z,r columns prescaled by log2e; h columns by 2*log2e (rec uses exp2 directly).
__global__ __launch_bounds__(256) void prep_kernel(
    const float* __restrict__ Kf, const float* __restrict__ Kb,
    const float* __restrict__ bfw, const float* __restrict__ bbw,
    ushortT* __restrict__ Wt, float* __restrict__ b0)
{
  int idx = blockIdx.x * 256 + threadIdx.x;
  if (idx < 2 * XPW * D_DIM) {
    int l = idx / (XPW * D_DIM);
    int rem = idx % (XPW * D_DIM);
    int c = rem / D_DIM, k = rem % D_DIM;
    float v = (c < TU) ? Kf[(size_t)l * D_DIM * TU + (size_t)k * TU + c]
                       : Kb[(size_t)l * D_DIM * TU + (size_t)k * TU + (c - TU)];
    float sc = ((c % TU) < 256) ? LOG2E_F : 2.0f * LOG2E_F;
    Wt[idx] = f2bf(v * sc);
  } else {
    int i2 = idx - 2 * XPW * D_DIM;
    if (i2 < 2 * XPW) {
      int l = i2 / XPW, c = i2 % XPW;
      float v = (c < TU) ? bfw[l * 2 * TU + c] : bbw[l * 2 * TU + (c - TU)];
      float sc = ((c % TU) < 256) ? LOG2E_F : 2.0f * LOG2E_F;
      b0[i2] = v * sc;
    }
  }
}

// ---------------- nodeof[g][slot] = node index ; L[g] = leaf count (positions are a perm of 1..L)
__global__ __launch_bounds__(256) void nodeofL_kernel(
    const int* __restrict__ pos, int* __restrict__ nodeof, int* __restrict__ L)
{
  int g = blockIdx.x, tid = threadIdx.x;
  __shared__ int red[256];
  int cnt = 0;
  for (int i = 0; i < NPER / 256; ++i) {
    int t = g * NPER + i * 256 + tid;
    int p = pos[t];
    if (p) { nodeof[g * NPER + p - 1] = t; cnt++; }
  }
  red[tid] = cnt; __syncthreads();
  for (int s = 128; s > 0; s >>= 1) {
    if (tid < s) red[tid] += red[tid + s];
    __syncthreads();
  }
  if (tid == 0) L[g] = red[0];
}

#if __has_builtin(__builtin_amdgcn_global_load_lds)
#define GLD_LDS(gsrc, ldst) \
  __builtin_amdgcn_global_load_lds((const GAS void*)(gsrc), \
                                   (__attribute__((address_space(3))) void*)(ldst), 16, 0, 0)
#define HAVE_GLD_LDS 1
#else
#define HAVE_GLD_LDS 0
#endif

// ---------------- xp[row][768] = A[row][0..255] @ Wt^T + b0   (bf16 MFMA, 128x128 tiles, BK=32)
// mode 0: A row r gathered from states (f32 -> bf16) via nodeof ; mode 1: A = dense bf16 (y)
__global__ __launch_bounds__(256) void gemm_kernel(
    const float* __restrict__ statesA, const ushortT* __restrict__ Adense,
    const ushortT* __restrict__ Wt, const float* __restrict__ b0,
    const int* __restrict__ nodeof, const int* __restrict__ L,
    ushortT* __restrict__ xp, int layer, int mode)
{
  int mblk = blockIdx.x, nblk = blockIdx.y;
  int g = mblk >> 4;
  int sBase = (mblk & 15) << 7;
  int Lg = L[g];
  if (sBase >= Lg) return;   // whole row-block is padding

  __shared__ __align__(16) ushortT As[128 * 32];
  __shared__ __align__(16) ushortT Bs[128 * 32];

  int tid = threadIdx.x;
  int lane = tid & 63, wid = tid >> 6;
  int wr = wid >> 1, wc = wid & 1;
  f32x4 acc[4][4];
  for (int i = 0; i < 4; i++) for (int n = 0; n < 4; n++) acc[i][n] = (f32x4){0.f,0.f,0.f,0.f};

  for (int kb = 0; kb < 8; ++kb) {
    __syncthreads();
    // stage B: Wt tile [128 cols][32 k] (Wt is pre-transposed: row=col, 512B row stride)
    for (int c = 0; c < 2; ++c) {
      int flat = c * 4096 + tid * 16;
      int col = flat >> 6;
      size_t srcB = ((size_t)(layer * XPW + nblk * 128 + col)) * 512 + kb * 64 + (flat & 63);
#if HAVE_GLD_LDS
      GLD_LDS((const char*)Wt + srcB, (char*)Bs + c * 4096 + wid * 1024);
#else
      *(uint4*)((char*)Bs + flat) = *(const uint4*)((const char*)Wt + srcB);
#endif
    }
    // stage A
    if (mode) {
      for (int c = 0; c < 2; ++c) {
        int flat = c * 4096 + tid * 16;
        int row = flat >> 6;
        size_t srcA = ((size_t)(mblk * 128 + row)) * 512 + kb * 64 + (flat & 63);
#if HAVE_GLD_LDS
        GLD_LDS((const char*)Adense + srcA, (char*)As + c * 4096 + wid * 1024);
#else
        *(uint4*)((char*)As + flat) = *(const uint4*)((const char*)Adense + srcA);
#endif
      }
    } else {
      for (int c = 0; c < 2; ++c) {
        int flat = c * 4096 + tid * 16;
        int row = flat >> 6;
        int s = sBase + row;
        if (s < Lg) {
          int nt = nodeof[g * NPER + s];
          const float* sp = statesA + (size_t)nt * D_DIM + kb * 32 + ((flat & 63) >> 1);
          float4 u0 = *(const float4*)sp;
          float4 u1 = *(const float4*)(sp + 4);
          union { ushortT us[8]; uint4 v; } pk;
          pk.us[0] = f2bf(u0.x); pk.us[1] = f2bf(u0.y); pk.us[2] = f2bf(u0.z); pk.us[3] = f2bf(u0.w);
          pk.us[4] = f2bf(u1.x); pk.us[5] = f2bf(u1.y); pk.us[6] = f2bf(u1.z); pk.us[7] = f2bf(u1.w);
          *(uint4*)((char*)As + flat) = pk.v;
        }
      }
    }
    __syncthreads();

    bf16x8 af[4], bfr[4];
    for (int i = 0; i < 4; i++) {
      int off = (wr * 64 + i * 16 + (lane & 15)) * 32 + (lane >> 4) * 8;
      af[i] = *(const bf16x8*)&As[off];
    }
    for (int n = 0; n < 4; n++) {
      int off = (wc * 64 + n * 16 + (lane & 15)) * 32 + (lane >> 4) * 8;
      bfr[n] = *(const bf16x8*)&Bs[off];
    }
    for (int i = 0; i < 4; i++)
      for (int n = 0; n < 4; n++)
        acc[i][n] = __builtin_amdgcn_mfma_f32_16x16x32_bf16(af[i], bfr[n], acc[i][n], 0, 0, 0);
  }

  // epilogue: + bias, store bf16.  C/D layout: col = lane&15, row = (lane>>4)*4 + v
  for (int n = 0; n < 4; n++) {
    int gcol = nblk * 128 + wc * 64 + n * 16 + (lane & 15);
    float bb = b0[layer * XPW + gcol];
    for (int i = 0; i < 4; i++) {
      int rowBase = mblk * 128 + wr * 64 + i * 16 + (lane >> 4) * 4;
      for (int v = 0; v < 4; v++)
        xp[(size_t)(rowBase + v) * XPW + gcol] = f2bf(acc[i][n][v] + bb);
    }
  }
}

// ---------------- recurrence: 1 WG (2 waves, 128 thr) per (graph, dir).
// Lane j (0..127) owns GRU unit j with FULL K=128: 3 gate cols {j,128+j,256+j},
// 64 f16x2 R-regs per gate (192 VGPR). NO cross-lane shuffles (r5's K-half split
// paid 3 ds_bpermute/step); gate math once per unit. h exchanged via ping-pong LDS
// (2B write/lane, 16 broadcast b128 reads); ONE raw s_barrier per step syncing just
// 2 waves, lgkmcnt-only drain (xp loads / y stores vmcnt-only, stay in flight).
// R/K/b prescaled by log2e (z,r) / 2log2e (h) -> exp2 gates. Depth-4 xp prefetch.
__global__ __launch_bounds__(128) void rec_kernel(
    const ushortT* __restrict__ xp,
    const float* __restrict__ Rf, const float* __restrict__ Rb,
    const float* __restrict__ bfw, const float* __restrict__ bbw,
    const int* __restrict__ L, ushortT* __restrict__ y, int layer)
{
  int g = blockIdx.x, dir = blockIdx.y;
  int Lg = L[g];
  if (Lg == 0) return;
  int j = threadIdx.x;                  // 0..127 = GRU unit

  __shared__ __align__(16) f16 hpk[2][128];

  const float* Rsrc = (dir ? Rb : Rf) + (size_t)layer * U_DIM * TU;
  const float* b1p  = (dir ? bbw : bfw) + layer * 2 * TU + TU;

  // recurrent weights into registers (f16x2 over k-pairs, full K, prescaled)
  f16x2 rz[64], rg[64], rh[64];
  #pragma unroll
  for (int m = 0; m < 64; ++m) {
    int k = 2 * m;
    const float* p0 = Rsrc + (size_t)k * TU;
    const float* p1 = p0 + TU;
    f16x2 a, b, c;
    a.x = (f16)(p0[j] * LOG2E_F);                a.y = (f16)(p1[j] * LOG2E_F);
    b.x = (f16)(p0[128 + j] * LOG2E_F);          b.y = (f16)(p1[128 + j] * LOG2E_F);
    c.x = (f16)(p0[256 + j] * (2.0f * LOG2E_F)); c.y = (f16)(p1[256 + j] * (2.0f * LOG2E_F));
    rz[m] = a; rg[m] = b; rh[m] = c;
  }
  float bz = b1p[j] * LOG2E_F;
  float br = b1p[128 + j] * LOG2E_F;
  float bh = b1p[256 + j] * (2.0f * LOG2E_F);

  hpk[0][j] = (f16)0.0f;
  float hreg = 0.0f;
  __syncthreads();

  size_t xbase = (size_t)g * NPER * XPW + (size_t)dir * TU;
  // depth-4 rolling prefetch
  ushortT xz0=0,xr0=0,xh0=0, xz1=0,xr1=0,xh1=0, xz2=0,xr2=0,xh2=0, xz3=0,xr3=0,xh3=0;
  {
    const ushortT* p;
    if (0 < Lg) { p = xp + xbase + (size_t)(dir ? Lg-1 : 0) * XPW;
                  xz0 = gload_u16(p+j); xr0 = gload_u16(p+128+j); xh0 = gload_u16(p+256+j); }
    if (1 < Lg) { p = xp + xbase + (size_t)(dir ? Lg-2 : 1) * XPW;
                  xz1 = gload_u16(p+j); xr1 = gload_u16(p+128+j); xh1 = gload_u16(p+256+j); }
    if (2 < Lg) { p = xp + xbase + (size_t)(dir ? Lg-3 : 2) * XPW;
                  xz2 = gload_u16(p+j); xr2 = gload_u16(p+128+j); xh2 = gload_u16(p+256+j); }
    if (3 < Lg) { p = xp + xbase + (size_t)(dir ? Lg-4 : 3) * XPW;
                  xz3 = gload_u16(p+j); xr3 = gload_u16(p+128+j); xh3 = gload_u16(p+256+j); }
  }

#define GRU_STEP(P, XZ, XR, XH, SS)                                              \
  {                                                                              \
    const int s_ = (SS);                                                         \
    float xzf = bf2f(XZ), xrf = bf2f(XR), xhf = bf2f(XH);                        \
    const int sp_ = s_ + 4;                                                      \
    if (sp_ < Lg) {                                                              \
      int pos2 = dir ? (Lg - 1 - sp_) : sp_;                                     \
      const ushortT* p_ = xp + xbase + (size_t)pos2 * XPW;                       \
      XZ = gload_u16(p_ + j);                                                    \
      XR = gload_u16(p_ + 128 + j);                                              \
      XH = gload_u16(p_ + 256 + j);                                              \
    }                                                                            \
    float az0 = bz, ar0 = br, ah0 = bh, az1 = 0.f, ar1 = 0.f, ah1 = 0.f;         \
    _Pragma("unroll")                                                            \
    for (int ho = 0; ho < 2; ++ho) {                                             \
      const uint4* hv = (const uint4*)&hpk[P][ho * 64];                          \
      uint32 hw[32];                                                             \
      _Pragma("unroll")                                                          \
      for (int q8 = 0; q8 < 8; ++q8) {                                           \
        uint4 v_ = hv[q8];                                                       \
        hw[4*q8] = v_.x; hw[4*q8+1] = v_.y; hw[4*q8+2] = v_.z; hw[4*q8+3] = v_.w;\
      }                                                                          \
      _Pragma("unroll")                                                          \
      for (int m = 0; m < 32; m += 2) {                                          \
        int mi = ho * 32 + m;                                                    \
        az0 = dot2f(u2h(hw[m]),   rz[mi],   az0);                                \
        ar0 = dot2f(u2h(hw[m]),   rg[mi],   ar0);                                \
        ah0 = dot2f(u2h(hw[m]),   rh[mi],   ah0);                                \
        az1 = dot2f(u2h(hw[m+1]), rz[mi+1], az1);                                \
        ar1 = dot2f(u2h(hw[m+1]), rg[mi+1], ar1);                                \
        ah1 = dot2f(u2h(hw[m+1]), rh[mi+1], ah1);                                \
      }                                                                          \
    }                                                                            \
    float hz = az0 + az1, hr = ar0 + ar1, hh = ah0 + ah1;                        \
    float z = rcpf(1.0f + exp2f_hw(-(xzf + hz)));                                \
    float r = rcpf(1.0f + exp2f_hw(-(xrf + hr)));                                \
    float a = xhf + r * hh;                                                      \
    float e = exp2f_hw(__builtin_fabsf(a));                                      \
    float th = 1.0f - 2.0f * rcpf(e + 1.0f);                                     \
    float cand = __builtin_copysignf(th, a);                                     \
    float hnew = cand + z * (hreg - cand);                                       \
    hreg = hnew;                                                                 \
    int pos_ = dir ? (Lg - 1 - s_) : s_;                                         \
    gstore_u16(y + (size_t)(g * NPER + pos_) * D_DIM + dir * U_DIM + j,          \
               f2bf(hnew));                                                      \
    hpk[(P) ^ 1][j] = (f16)hnew;                                                 \
    asm volatile("s_waitcnt lgkmcnt(0)" ::: "memory");                           \
    __builtin_amdgcn_sched_barrier(0);                                           \
    __builtin_amdgcn_s_barrier();                                                \
    __builtin_amdgcn_sched_barrier(0);                                           \
  }

  for (int s = 0; s < Lg; s += 4) {
    GRU_STEP(0, xz0, xr0, xh0, s);
    if (s + 1 < Lg) GRU_STEP(1, xz1, xr1, xh1, s + 1);
    if (s + 2 < Lg) GRU_STEP(0, xz2, xr2, xh2, s + 2);
    if (s + 3 < Lg) GRU_STEP(1, xz3, xr3, xh3, s + 3);
  }
#undef GRU_STEP
}

// ---------------- unpack: leaf -> y (bf16->f32), non-leaf -> states copy
__global__ __launch_bounds__(256) void unpack_kernel(
    const float* __restrict__ states, const int* __restrict__ pos,
    const ushortT* __restrict__ y, float* __restrict__ out)
{
  int node = blockIdx.x * 4 + (threadIdx.x >> 6);
  int lane = threadIdx.x & 63;
  int p = pos[node];
  int g = node >> 11;
  float4 v;
  if (p) {
    const ushortT* yp = y + (size_t)(g * NPER + p - 1) * D_DIM + lane * 4;
    v = make_float4(bf2f(yp[0]), bf2f(yp[1]), bf2f(yp[2]), bf2f(yp[3]));
  } else {
    v = *(const float4*)(states + (size_t)node * D_DIM + lane * 4);
  }
  *(float4*)(out + (size_t)node * D_DIM + lane * 4) = v;
}

extern "C" void kernel_launch(void* const* d_in, const int* in_sizes, int n_in,
                              void* d_out, int out_size, void* d_ws, size_t ws_size,
                              hipStream_t stream) {
  const float* states = (const float*)d_in[0];
  const int*   pos    = (const int*)d_in[1];
  // d_in[2] graph_sizes (uniform 2048), d_in[3] training (0) — unused
  const float* Kf  = (const float*)d_in[4];
  const float* Rf  = (const float*)d_in[5];
  const float* bfw = (const float*)d_in[6];
  const float* Kb  = (const float*)d_in[7];
  const float* Rb  = (const float*)d_in[8];
  const float* bbw = (const float*)d_in[9];

  char* ws = (char*)d_ws;
  // layout: L(256B) | nodeof(512KB) | Wt(768KB) | b0(6KB) | xp(201.3MB) | y(67.1MB)  ~= 270MB
  int*     L      = (int*)(ws + 0);
  int*     nodeof = (int*)(ws + 256);
  ushortT* Wt     = (ushortT*)(ws + 524544);
  float*   b0     = (float*)(ws + 1310976);
  ushortT* xp     = (ushortT*)(ws + 1317120);
  ushortT* y      = (ushortT*)(ws + 202643712);

  prep_kernel<<<1542, 256, 0, stream>>>(Kf, Kb, bfw, bbw, Wt, b0);
  nodeofL_kernel<<<64, 256, 0, stream>>>(pos, nodeof, L);

  dim3 ggrid(1024, 6);
  dim3 rgrid(64, 2);   // 1 chain per WG, 2 waves each

  // layer 0
  gemm_kernel<<<ggrid, 256, 0, stream>>>(states, (const ushortT*)nullptr, Wt, b0, nodeof, L, xp, 0, 0);
  rec_kernel<<<rgrid, 128, 0, stream>>>(xp, Rf, Rb, bfw, bbw, L, y, 0);
  // layer 1
  gemm_kernel<<<ggrid, 256, 0, stream>>>(states, y, Wt, b0, nodeof, L, xp, 1, 1);
  rec_kernel<<<rgrid, 128, 0, stream>>>(xp, Rf, Rb, bfw, bbw, L, y, 1);

  unpack_kernel<<<32768, 256, 0, stream>>>(states, pos, y, (float*)d_out);
}

// Round 12
// 1239.723 us; speedup vs baseline: 2.2656x; 1.2812x over previous
//
#include <hip/hip_runtime.h>
#include <hip/hip_bf16.h>

#define B_GRAPHS 64
#define NPER     2048
#define T_NODES  (B_GRAPHS*NPER)
#define D_DIM    256
#define U_DIM    128
#define TU       384   // 3*U
#define XPW      768   // 2*TU (fwd|bwd)

typedef unsigned short ushortT;
typedef unsigned int   uint32;

typedef __attribute__((ext_vector_type(4))) float  f32x4;
typedef __attribute__((ext_vector_type(8))) __bf16 bf16x8;
typedef _Float16 f16;
typedef __attribute__((ext_vector_type(2))) _Float16 f16x2;

#define GAS __attribute__((address_space(1)))
#define LOG2E_F 1.4426950408889634f

static __device__ __forceinline__ ushortT f2bf(float f) {
  union { float f; uint32 u; } a; a.f = f;
  uint32 u = a.u;
  return (ushortT)((u + 0x7fffu + ((u >> 16) & 1u)) >> 16);   // RTNE
}
static __device__ __forceinline__ float bf2f(ushortT h) {
  union { uint32 u; float f; } a; a.u = ((uint32)h) << 16; return a.f;
}
static __device__ __forceinline__ f16x2 u2h(uint32 u) {
  union { uint32 u; f16x2 h; } x; x.u = u; return x.h;
}
static __device__ __forceinline__ float dot2f(f16x2 a, f16x2 b, float c) {
#if __has_builtin(__builtin_amdgcn_fdot2)
  return __builtin_amdgcn_fdot2(a, b, c, false);
#else
  return c + (float)a.x * (float)b.x + (float)a.y * (float)b.y;
#endif
}
static __device__ __forceinline__ float rcpf(float x) {
#if __has_builtin(__builtin_amdgcn_rcpf)
  return __builtin_amdgcn_rcpf(x);
#else
  return 1.0f / x;
#endif
}
static __device__ __forceinline__ float exp2f_hw(float x) {
#if __has_builtin(__builtin_amdgcn_exp2f)
  return __builtin_amdgcn_exp2f(x);
#else
  return __expf(0.69314718055994531f * x);
#endif
}
static __device__ __forceinline__ ushortT gload_u16(const ushortT* p) {
  return *(const GAS ushortT*)p;
}
static __device__ __forceinline__ void gstore_u16(ushortT* p, ushortT v) {
  *(GAS ushortT*)p = v;
}

// sum over lane pairs (l, l^32): PROVEN path only. permlane32_swap failed
// identically in r3/r4/r11 (absmax ~0.5-0.69) -> permanently abandoned.
static __device__ __forceinline__ float xor32_sum(float v) {
  return v + __shfl_xor(v, 32);
}

// ---------------- prep: Wt[2][768][256] bf16 (transposed concat of K_fwd|K_bwd), b0[2][768] f32
// z,r columns prescaled by log2e; h columns by 2*log2e (rec uses exp2 directly).
__global__ __launch_bounds__(256) void prep_kernel(
    const float* __restrict__ Kf, const float* __restrict__ Kb,
    const float* __restrict__ bfw, const float* __restrict__ bbw,
    ushortT* __restrict__ Wt, float* __restrict__ b0)
{
  int idx = blockIdx.x * 256 + threadIdx.x;
  if (idx < 2 * XPW * D_DIM) {
    int l = idx / (XPW * D_DIM);
    int rem = idx % (XPW * D_DIM);
    int c = rem / D_DIM, k = rem % D_DIM;
    float v = (c < TU) ? Kf[(size_t)l * D_DIM * TU + (size_t)k * TU + c]
                       : Kb[(size_t)l * D_DIM * TU + (size_t)k * TU + (c - TU)];
    float sc = ((c % TU) < 256) ? LOG2E_F : 2.0f * LOG2E_F;
    Wt[idx] = f2bf(v * sc);
  } else {
    int i2 = idx - 2 * XPW * D_DIM;
    if (i2 < 2 * XPW) {
      int l = i2 / XPW, c = i2 % XPW;
      float v = (c < TU) ? bfw[l * 2 * TU + c] : bbw[l * 2 * TU + (c - TU)];
      float sc = ((c % TU) < 256) ? LOG2E_F : 2.0f * LOG2E_F;
      b0[i2] = v * sc;
    }
  }
}

// ---------------- nodeof[g][slot] = node index ; L[g] = leaf count (positions are a perm of 1..L)
__global__ __launch_bounds__(256) void nodeofL_kernel(
    const int* __restrict__ pos, int* __restrict__ nodeof, int* __restrict__ L)
{
  int g = blockIdx.x, tid = threadIdx.x;
  __shared__ int red[256];
  int cnt = 0;
  for (int i = 0; i < NPER / 256; ++i) {
    int t = g * NPER + i * 256 + tid;
    int p = pos[t];
    if (p) { nodeof[g * NPER + p - 1] = t; cnt++; }
  }
  red[tid] = cnt; __syncthreads();
  for (int s = 128; s > 0; s >>= 1) {
    if (tid < s) red[tid] += red[tid + s];
    __syncthreads();
  }
  if (tid == 0) L[g] = red[0];
}

#if __has_builtin(__builtin_amdgcn_global_load_lds)
#define GLD_LDS(gsrc, ldst) \
  __builtin_amdgcn_global_load_lds((const GAS void*)(gsrc), \
                                   (__attribute__((address_space(3))) void*)(ldst), 16, 0, 0)
#define HAVE_GLD_LDS 1
#else
#define HAVE_GLD_LDS 0
#endif

// ---------------- xp[row][768] = A[row][0..255] @ Wt^T + b0   (bf16 MFMA, 128x128 tiles, BK=32)
// mode 0: A row r gathered from states (f32 -> bf16) via nodeof ; mode 1: A = dense bf16 (y)
__global__ __launch_bounds__(256) void gemm_kernel(
    const float* __restrict__ statesA, const ushortT* __restrict__ Adense,
    const ushortT* __restrict__ Wt, const float* __restrict__ b0,
    const int* __restrict__ nodeof, const int* __restrict__ L,
    ushortT* __restrict__ xp, int layer, int mode)
{
  int mblk = blockIdx.x, nblk = blockIdx.y;
  int g = mblk >> 4;
  int sBase = (mblk & 15) << 7;
  int Lg = L[g];
  if (sBase >= Lg) return;   // whole row-block is padding

  __shared__ __align__(16) ushortT As[128 * 32];
  __shared__ __align__(16) ushortT Bs[128 * 32];

  int tid = threadIdx.x;
  int lane = tid & 63, wid = tid >> 6;
  int wr = wid >> 1, wc = wid & 1;
  f32x4 acc[4][4];
  for (int i = 0; i < 4; i++) for (int n = 0; n < 4; n++) acc[i][n] = (f32x4){0.f,0.f,0.f,0.f};

  for (int kb = 0; kb < 8; ++kb) {
    __syncthreads();
    // stage B: Wt tile [128 cols][32 k] (Wt is pre-transposed: row=col, 512B row stride)
    for (int c = 0; c < 2; ++c) {
      int flat = c * 4096 + tid * 16;
      int col = flat >> 6;
      size_t srcB = ((size_t)(layer * XPW + nblk * 128 + col)) * 512 + kb * 64 + (flat & 63);
#if HAVE_GLD_LDS
      GLD_LDS((const char*)Wt + srcB, (char*)Bs + c * 4096 + wid * 1024);
#else
      *(uint4*)((char*)Bs + flat) = *(const uint4*)((const char*)Wt + srcB);
#endif
    }
    // stage A
    if (mode) {
      for (int c = 0; c < 2; ++c) {
        int flat = c * 4096 + tid * 16;
        int row = flat >> 6;
        size_t srcA = ((size_t)(mblk * 128 + row)) * 512 + kb * 64 + (flat & 63);
#if HAVE_GLD_LDS
        GLD_LDS((const char*)Adense + srcA, (char*)As + c * 4096 + wid * 1024);
#else
        *(uint4*)((char*)As + flat) = *(const uint4*)((const char*)Adense + srcA);
#endif
      }
    } else {
      for (int c = 0; c < 2; ++c) {
        int flat = c * 4096 + tid * 16;
        int row = flat >> 6;
        int s = sBase + row;
        if (s < Lg) {
          int nt = nodeof[g * NPER + s];
          const float* sp = statesA + (size_t)nt * D_DIM + kb * 32 + ((flat & 63) >> 1);
          float4 u0 = *(const float4*)sp;
          float4 u1 = *(const float4*)(sp + 4);
          union { ushortT us[8]; uint4 v; } pk;
          pk.us[0] = f2bf(u0.x); pk.us[1] = f2bf(u0.y); pk.us[2] = f2bf(u0.z); pk.us[3] = f2bf(u0.w);
          pk.us[4] = f2bf(u1.x); pk.us[5] = f2bf(u1.y); pk.us[6] = f2bf(u1.z); pk.us[7] = f2bf(u1.w);
          *(uint4*)((char*)As + flat) = pk.v;
        }
      }
    }
    __syncthreads();

    bf16x8 af[4], bfr[4];
    for (int i = 0; i < 4; i++) {
      int off = (wr * 64 + i * 16 + (lane & 15)) * 32 + (lane >> 4) * 8;
      af[i] = *(const bf16x8*)&As[off];
    }
    for (int n = 0; n < 4; n++) {
      int off = (wc * 64 + n * 16 + (lane & 15)) * 32 + (lane >> 4) * 8;
      bfr[n] = *(const bf16x8*)&Bs[off];
    }
    for (int i = 0; i < 4; i++)
      for (int n = 0; n < 4; n++)
        acc[i][n] = __builtin_amdgcn_mfma_f32_16x16x32_bf16(af[i], bfr[n], acc[i][n], 0, 0, 0);
  }

  // epilogue: + bias, store bf16.  C/D layout: col = lane&15, row = (lane>>4)*4 + v
  for (int n = 0; n < 4; n++) {
    int gcol = nblk * 128 + wc * 64 + n * 16 + (lane & 15);
    float bb = b0[layer * XPW + gcol];
    for (int i = 0; i < 4; i++) {
      int rowBase = mblk * 128 + wr * 64 + i * 16 + (lane >> 4) * 4;
      for (int v = 0; v < 4; v++)
        xp[(size_t)(rowBase + v) * XPW + gcol] = f2bf(acc[i][n][v] + bb);
    }
  }
}

// ---------------- recurrence: 1 WG (4 waves, 256 thr) per (graph, dir) — round-5 skeleton.
// lane layout: j = wave*32+(lane&31) (GRU unit), half = lane>>5 (K half).
// Each lane: 3 gate cols {j,128+j,256+j}, 32 f16x2 R regs/gate (prescaled by log2e / 2log2e).
// K-half combine via __shfl_xor(32) (proven). h via ping-pong LDS, ONE raw s_barrier per
// step with lgkmcnt-only drain (xp loads / y stores vmcnt-only, stay in flight).
// Depth-4 xp prefetch with ROLLING pointers (no per-step 64-bit muls).
__global__ __launch_bounds__(256) void rec_kernel(
    const ushortT* __restrict__ xp,
    const float* __restrict__ Rf, const float* __restrict__ Rb,
    const float* __restrict__ bfw, const float* __restrict__ bbw,
    const int* __restrict__ L, ushortT* __restrict__ y, int layer)
{
  int g = blockIdx.x, dir = blockIdx.y;
  int Lg = L[g];
  if (Lg == 0) return;
  int tid = threadIdx.x;
  int wave = tid >> 6, lane = tid & 63;
  int jl = lane & 31, half = lane >> 5;
  int j = wave * 32 + jl;                 // 0..127

  __shared__ __align__(16) f16 hpk[2][128];

  const float* R  = (dir ? Rb : Rf) + (size_t)layer * U_DIM * TU;
  const float* b1 = (dir ? bbw : bfw) + layer * 2 * TU + TU;

  // recurrent weights into registers (f16x2 over k-pairs, prescaled)
  f16x2 rz[32], rg[32], rh[32];
  #pragma unroll
  for (int m = 0; m < 32; ++m) {
    int k = half * 64 + 2 * m;
    const float* p0 = R + (size_t)k * TU;
    const float* p1 = p0 + TU;
    f16x2 a, b, c;
    a.x = (f16)(p0[j] * LOG2E_F);                a.y = (f16)(p1[j] * LOG2E_F);
    b.x = (f16)(p0[128 + j] * LOG2E_F);          b.y = (f16)(p1[128 + j] * LOG2E_F);
    c.x = (f16)(p0[256 + j] * (2.0f * LOG2E_F)); c.y = (f16)(p1[256 + j] * (2.0f * LOG2E_F));
    rz[m] = a; rg[m] = b; rh[m] = c;
  }
  float bz = half ? 0.0f : b1[j] * LOG2E_F;
  float br = half ? 0.0f : b1[128 + j] * LOG2E_F;
  float bh = half ? 0.0f : b1[256 + j] * (2.0f * LOG2E_F);

  if (tid < 128) hpk[0][tid] = (f16)0.0f;
  float hreg = 0.0f;
  __syncthreads();

  size_t xbase = (size_t)g * NPER * XPW + (size_t)dir * TU;
  int pos0 = dir ? (Lg - 1) : 0;
  const int xstep = dir ? -XPW : XPW;
  const int ystep = dir ? -D_DIM : D_DIM;
  const ushortT* xnext = xp + xbase + (size_t)pos0 * XPW;     // rolling prefetch ptr
  ushortT* ynext = y + ((size_t)(g * NPER + pos0)) * D_DIM + dir * U_DIM + j;

  // depth-4 prologue (pointer advances unconditionally; loads guarded, so no OOB access)
  ushortT xz0=0,xr0=0,xh0=0, xz1=0,xr1=0,xh1=0, xz2=0,xr2=0,xh2=0, xz3=0,xr3=0,xh3=0;
  { xz0 = gload_u16(xnext+j); xr0 = gload_u16(xnext+128+j); xh0 = gload_u16(xnext+256+j); }
  xnext += xstep;
  if (1 < Lg) { xz1 = gload_u16(xnext+j); xr1 = gload_u16(xnext+128+j); xh1 = gload_u16(xnext+256+j); }
  xnext += xstep;
  if (2 < Lg) { xz2 = gload_u16(xnext+j); xr2 = gload_u16(xnext+128+j); xh2 = gload_u16(xnext+256+j); }
  xnext += xstep;
  if (3 < Lg) { xz3 = gload_u16(xnext+j); xr3 = gload_u16(xnext+128+j); xh3 = gload_u16(xnext+256+j); }
  xnext += xstep;

#define GRU_STEP(P, XZ, XR, XH, SS)                                              \
  {                                                                              \
    const int s_ = (SS);                                                         \
    float xzf = bf2f(XZ), xrf = bf2f(XR), xhf = bf2f(XH);                        \
    if (s_ + 4 < Lg) {                                                           \
      XZ = gload_u16(xnext + j);                                                 \
      XR = gload_u16(xnext + 128 + j);                                           \
      XH = gload_u16(xnext + 256 + j);                                           \
    }                                                                            \
    xnext += xstep;                                                              \
    const uint4* hv = (const uint4*)&hpk[P][half * 64];                          \
    uint32 hw[32];                                                               \
    _Pragma("unroll")                                                            \
    for (int q8 = 0; q8 < 8; ++q8) {                                             \
      uint4 v_ = hv[q8];                                                         \
      hw[4*q8] = v_.x; hw[4*q8+1] = v_.y; hw[4*q8+2] = v_.z; hw[4*q8+3] = v_.w;  \
    }                                                                            \
    float az0 = bz, ar0 = br, ah0 = bh, az1 = 0.f, ar1 = 0.f, ah1 = 0.f;         \
    _Pragma("unroll")                                                            \
    for (int m = 0; m < 32; m += 2) {                                            \
      az0 = dot2f(u2h(hw[m]),   rz[m],   az0);                                   \
      ar0 = dot2f(u2h(hw[m]),   rg[m],   ar0);                                   \
      ah0 = dot2f(u2h(hw[m]),   rh[m],   ah0);                                   \
      az1 = dot2f(u2h(hw[m+1]), rz[m+1], az1);                                   \
      ar1 = dot2f(u2h(hw[m+1]), rg[m+1], ar1);                                   \
      ah1 = dot2f(u2h(hw[m+1]), rh[m+1], ah1);                                   \
    }                                                                            \
    float hz = xor32_sum(az0 + az1);                                             \
    float hr = xor32_sum(ar0 + ar1);                                             \
    float hh = xor32_sum(ah0 + ah1);                                             \
    float z = rcpf(1.0f + exp2f_hw(-(xzf + hz)));                                \
    float r = rcpf(1.0f + exp2f_hw(-(xrf + hr)));                                \
    float a = xhf + r * hh;                                                      \
    float e = exp2f_hw(__builtin_fabsf(a));                                      \
    float th = 1.0f - 2.0f * rcpf(e + 1.0f);                                     \
    float cand = __builtin_copysignf(th, a);                                     \
    float hnew = cand + z * (hreg - cand);                                       \
    hreg = hnew;                                                                 \
    if (half) {                                                                  \
      gstore_u16(ynext, f2bf(hnew));                                             \
    } else {                                                                     \
      hpk[(P) ^ 1][j] = (f16)hnew;                                               \
    }                                                                            \
    ynext += ystep;                                                              \
    asm volatile("s_waitcnt lgkmcnt(0)" ::: "memory");                           \
    __builtin_amdgcn_sched_barrier(0);                                           \
    __builtin_amdgcn_s_barrier();                                                \
    __builtin_amdgcn_sched_barrier(0);                                           \
  }

  for (int s = 0; s < Lg; s += 4) {
    GRU_STEP(0, xz0, xr0, xh0, s);
    if (s + 1 < Lg) GRU_STEP(1, xz1, xr1, xh1, s + 1);
    if (s + 2 < Lg) GRU_STEP(0, xz2, xr2, xh2, s + 2);
    if (s + 3 < Lg) GRU_STEP(1, xz3, xr3, xh3, s + 3);
  }
#undef GRU_STEP
}

// ---------------- unpack: leaf -> y (bf16->f32), non-leaf -> states copy
__global__ __launch_bounds__(256) void unpack_kernel(
    const float* __restrict__ states, const int* __restrict__ pos,
    const ushortT* __restrict__ y, float* __restrict__ out)
{
  int node = blockIdx.x * 4 + (threadIdx.x >> 6);
  int lane = threadIdx.x & 63;
  int p = pos[node];
  int g = node >> 11;
  float4 v;
  if (p) {
    const ushortT* yp = y + (size_t)(g * NPER + p - 1) * D_DIM + lane * 4;
    v = make_float4(bf2f(yp[0]), bf2f(yp[1]), bf2f(yp[2]), bf2f(yp[3]));
  } else {
    v = *(const float4*)(states + (size_t)node * D_DIM + lane * 4);
  }
  *(float4*)(out + (size_t)node * D_DIM + lane * 4) = v;
}

extern "C" void kernel_launch(void* const* d_in, const int* in_sizes, int n_in,
                              void* d_out, int out_size, void* d_ws, size_t ws_size,
                              hipStream_t stream) {
  const float* states = (const float*)d_in[0];
  const int*   pos    = (const int*)d_in[1];
  // d_in[2] graph_sizes (uniform 2048), d_in[3] training (0) — unused
  const float* Kf  = (const float*)d_in[4];
  const float* Rf  = (const float*)d_in[5];
  const float* bfw = (const float*)d_in[6];
  const float* Kb  = (const float*)d_in[7];
  const float* Rb  = (const float*)d_in[8];
  const float* bbw = (const float*)d_in[9];

  char* ws = (char*)d_ws;
  // layout: L(256B) | nodeof(512KB) | Wt(768KB) | b0(6KB) | xp(201.3MB) | y(67.1MB)  ~= 270MB
  int*     L      = (int*)(ws + 0);
  int*     nodeof = (int*)(ws + 256);
  ushortT* Wt     = (ushortT*)(ws + 524544);
  float*   b0     = (float*)(ws + 1310976);
  ushortT* xp     = (ushortT*)(ws + 1317120);
  ushortT* y      = (ushortT*)(ws + 202643712);

  prep_kernel<<<1542, 256, 0, stream>>>(Kf, Kb, bfw, bbw, Wt, b0);
  nodeofL_kernel<<<64, 256, 0, stream>>>(pos, nodeof, L);

  dim3 ggrid(1024, 6);
  dim3 rgrid(64, 2);   // 1 chain per WG (minimal step latency is the only lever)

  // layer 0
  gemm_kernel<<<ggrid, 256, 0, stream>>>(states, (const ushortT*)nullptr, Wt, b0, nodeof, L, xp, 0, 0);
  rec_kernel<<<rgrid, 256, 0, stream>>>(xp, Rf, Rb, bfw, bbw, L, y, 0);
  // layer 1
  gemm_kernel<<<ggrid, 256, 0, stream>>>(states, y, Wt, b0, nodeof, L, xp, 1, 1);
  rec_kernel<<<rgrid, 256, 0, stream>>>(xp, Rf, Rb, bfw, bbw, L, y, 1);

  unpack_kernel<<<32768, 256, 0, stream>>>(states, pos, y, (float*)d_out);
}